// Round 5
// baseline (435.101 us; speedup 1.0000x reference)
//
#include <hip/hip_runtime.h>

typedef unsigned long long u64;

#define F_IN 512
#define HID 128
#define CLS 64
#define EPS 1e-5f
#define NSB 512   // col_stats partial blocks

// ---------------- column stats: per-block partials, NO atomics --------------
__global__ __launch_bounds__(256) void col_stats_k(const float4* __restrict__ x4,
                                                   float* __restrict__ psum,
                                                   float* __restrict__ psq,
                                                   int n, int rpb) {
    __shared__ float red[256][9];        // pad 9: spread banks
    int c4 = threadIdx.x & 127;          // column quad 0..127
    int half = threadIdx.x >> 7;         // 0/1 row interleave
    int r0 = blockIdx.x * rpb;
    int r1 = min(n, r0 + rpb);
    float s0=0.f,s1=0.f,s2=0.f,s3=0.f,q0=0.f,q1=0.f,q2=0.f,q3=0.f;
#pragma unroll 4
    for (int r = r0 + half; r < r1; r += 2) {
        float4 v = x4[(size_t)r * 128 + c4];
        s0 += v.x; q0 += v.x * v.x;
        s1 += v.y; q1 += v.y * v.y;
        s2 += v.z; q2 += v.z * v.z;
        s3 += v.w; q3 += v.w * v.w;
    }
    red[threadIdx.x][0]=s0; red[threadIdx.x][1]=s1; red[threadIdx.x][2]=s2; red[threadIdx.x][3]=s3;
    red[threadIdx.x][4]=q0; red[threadIdx.x][5]=q1; red[threadIdx.x][6]=q2; red[threadIdx.x][7]=q3;
    __syncthreads();
    if (half == 0) {
        int c = c4 * 4;
        float* os = &psum[(size_t)blockIdx.x * 512 + c];
        float* oq = &psq [(size_t)blockIdx.x * 512 + c];
        os[0] = s0 + red[c4+128][0]; os[1] = s1 + red[c4+128][1];
        os[2] = s2 + red[c4+128][2]; os[3] = s3 + red[c4+128][3];
        oq[0] = q0 + red[c4+128][4]; oq[1] = q1 + red[c4+128][5];
        oq[2] = q2 + red[c4+128][6]; oq[3] = q3 + red[c4+128][7];
    }
}

// ---------------- reduce partials -> mu, rinv (fused finalize) --------------
__global__ __launch_bounds__(256) void stats_reduce_k(const float* __restrict__ psum,
                                                      const float* __restrict__ psq,
                                                      float* __restrict__ mu,
                                                      float* __restrict__ rinv, int n) {
    __shared__ float reds[256], redq[256];
    int cc = threadIdx.x & 31;
    int bs = threadIdx.x >> 5;           // 0..7 b-slice
    int c = blockIdx.x * 32 + cc;        // 16 blocks x 32 cols
    float s = 0.f, q = 0.f;
#pragma unroll 4
    for (int b = bs; b < NSB; b += 8) {
        s += psum[(size_t)b * 512 + c];
        q += psq [(size_t)b * 512 + c];
    }
    reds[threadIdx.x] = s; redq[threadIdx.x] = q;
    __syncthreads();
    if (bs == 0) {
#pragma unroll
        for (int t = 1; t < 8; ++t) { s += reds[cc + 32*t]; q += redq[cc + 32*t]; }
        float m = s / (float)n;
        float v = q / (float)n - m * m;
        mu[c] = m;
        rinv[c] = rsqrtf(v + EPS);
    }
}

// ---- W1 pack. Feature->bit map (matches bin1 float4 loads):
//      word jw<4 : bit l = feature 4l+jw ; word jw>=4 : bit l = feature 256+4l+jw-4
__global__ __launch_bounds__(64) void pack_w1_k(const float* __restrict__ W,
                                                u64* __restrict__ sig,
                                                float* __restrict__ beta) {
    int j = blockIdx.x;    // hidden col 0..127
    int l = threadIdx.x;   // 0..63
    float asum = 0.f;
#pragma unroll
    for (int jw = 0; jw < 8; ++jw) {
        int f = (jw < 4) ? (4*l + jw) : (256 + 4*l + (jw - 4));
        float v = W[(size_t)f * HID + j];
        asum += fabsf(v);
        u64 b = __ballot(v > 0.0f);
        if (l == 0) sig[jw * HID + j] = b;
    }
    for (int m = 32; m >= 1; m >>= 1) asum += __shfl_xor(asum, m);
    if (l == 0) beta[j] = asum * (1.0f / 512.0f);
}

// ---- W2 pack -> sw4[g*256 + j*4 + m] = sign(W2[4g+m][j]) * beta2_j ---------
__global__ __launch_bounds__(64) void pack_w2_k(const float* __restrict__ W,
                                                float* __restrict__ sw4) {
    int j = blockIdx.x;    // class 0..63
    int l = threadIdx.x;   // features l, l+64
    float v0 = W[(size_t)l * CLS + j];
    float v1 = W[(size_t)(l + 64) * CLS + j];
    float asum = fabsf(v0) + fabsf(v1);
    for (int m = 32; m >= 1; m >>= 1) asum += __shfl_xor(asum, m);
    float beta = asum * (1.0f / 128.0f);
    int f0 = l, f1 = l + 64;
    sw4[(f0 >> 2) * 256 + j * 4 + (f0 & 3)] = (v0 > 0.f) ? beta : -beta;
    sw4[(f1 >> 2) * 256 + j * 4 + (f1 & 3)] = (v1 > 0.f) ? beta : -beta;
}

// ---------------- degree ----------------
__global__ __launch_bounds__(256) void deg_k(const int* __restrict__ col,
                                             int* __restrict__ deg, int e) {
    int i = blockIdx.x * blockDim.x + threadIdx.x;
    if (i < e) atomicAdd(&deg[col[i]], 1);
}

// ---------------- exclusive scan of deg -> CSR offsets (+dinv fused) --------
__global__ __launch_bounds__(256) void scan_partial_k(const int* __restrict__ deg,
                                                      int* __restrict__ bsum, int n) {
    __shared__ int lds[256];
    int i = blockIdx.x * 256 + threadIdx.x;
    lds[threadIdx.x] = (i < n) ? deg[i] : 0;
    __syncthreads();
    for (int s = 128; s > 0; s >>= 1) {
        if (threadIdx.x < s) lds[threadIdx.x] += lds[threadIdx.x + s];
        __syncthreads();
    }
    if (threadIdx.x == 0) bsum[blockIdx.x] = lds[0];
}

__global__ __launch_bounds__(256) void scan_bsum_k(const int* __restrict__ bsum,
                                                   int* __restrict__ boff, int nb) {
    __shared__ int lds[256];
    int t = threadIdx.x;
    int v = (t < nb) ? bsum[t] : 0;
    lds[t] = v;
    __syncthreads();
    for (int s = 1; s < 256; s <<= 1) {
        int add = (t >= s) ? lds[t - s] : 0;
        __syncthreads();
        lds[t] += add;
        __syncthreads();
    }
    if (t < nb) boff[t] = lds[t] - v;   // exclusive
}

__global__ __launch_bounds__(256) void scan_final_k(const int* __restrict__ deg,
                                                    const int* __restrict__ boff,
                                                    int* __restrict__ offs,
                                                    int* __restrict__ cursor,
                                                    float* __restrict__ dinv, int n) {
    __shared__ int lds[256];
    int t = threadIdx.x;
    int i = blockIdx.x * 256 + t;
    int v = (i < n) ? deg[i] : 0;
    lds[t] = v;
    __syncthreads();
    for (int s = 1; s < 256; s <<= 1) {
        int add = (t >= s) ? lds[t - s] : 0;
        __syncthreads();
        lds[t] += add;
        __syncthreads();
    }
    int excl = lds[t] - v + boff[blockIdx.x];
    if (i < n) {
        offs[i] = excl; cursor[i] = excl;
        dinv[i] = rsqrtf((float)v + 1.0f);   // +1 self-loop
    }
}

// ---------------- layer 1: binarize + XNOR-GEMM -> int16 dots + a1 ----------
__global__ __launch_bounds__(256) void bin1_gemm1_k(const float4* __restrict__ x4,
                                                    const float4* __restrict__ mu4,
                                                    const float4* __restrict__ rinv4,
                                                    const u64* __restrict__ sigW,
                                                    float* __restrict__ a1,
                                                    short2* __restrict__ dots, int n) {
    int tid = threadIdx.x;
    int wave = tid >> 6, l = tid & 63;
    int i = blockIdx.x * 4 + wave;
    if (i >= n) return;
    const float4* xr = x4 + (size_t)i * 128;
    float4 va = xr[l], vb = xr[64 + l];          // features 4l..4l+3, 256+4l..+3
    float4 ma = mu4[l], mb = mu4[64 + l];
    float4 ra = rinv4[l], rb = rinv4[64 + l];
    float t0 = va.x - ma.x, t1 = va.y - ma.y, t2 = va.z - ma.z, t3 = va.w - ma.w;
    float t4 = vb.x - mb.x, t5 = vb.y - mb.y, t6 = vb.z - mb.z, t7 = vb.w - mb.w;
    float asum = fabsf(t0)*ra.x + fabsf(t1)*ra.y + fabsf(t2)*ra.z + fabsf(t3)*ra.w
               + fabsf(t4)*rb.x + fabsf(t5)*rb.y + fabsf(t6)*rb.z + fabsf(t7)*rb.w;
    u64 sx[8];
    sx[0] = __ballot(t0 > 0.f); sx[1] = __ballot(t1 > 0.f);
    sx[2] = __ballot(t2 > 0.f); sx[3] = __ballot(t3 > 0.f);
    sx[4] = __ballot(t4 > 0.f); sx[5] = __ballot(t5 > 0.f);
    sx[6] = __ballot(t6 > 0.f); sx[7] = __ballot(t7 > 0.f);
    for (int m = 32; m >= 1; m >>= 1) asum += __shfl_xor(asum, m);
    if (l == 0) a1[i] = asum * (1.0f / 512.0f);
    int c0 = 0, c1 = 0;
#pragma unroll
    for (int w = 0; w < 8; ++w) {
        c0 += __popcll(sx[w] ^ sigW[w * HID + 2*l]);
        c1 += __popcll(sx[w] ^ sigW[w * HID + 2*l + 1]);
    }
    dots[(size_t)i * 64 + l] = make_short2((short)(512 - 2*c0), (short)(512 - 2*c1));
}

// ---- CSR fill: {r, w*a1[r]} for layer1, {r, w} for rebake ------------------
__global__ __launch_bounds__(256) void fill_k(const int* __restrict__ row,
                                              const int* __restrict__ col,
                                              const float* __restrict__ dinv,
                                              const float* __restrict__ a1,
                                              int* __restrict__ cursor,
                                              int2* __restrict__ csr1,
                                              int2* __restrict__ csrw, int e) {
    int i = blockIdx.x * blockDim.x + threadIdx.x;
    if (i < e) {
        int r = row[i], c = col[i];
        int p = atomicAdd(&cursor[c], 1);
        float w = dinv[r] * dinv[c];
        csr1[p] = make_int2(r, __float_as_int(w * a1[r]));
        csrw[p] = make_int2(r, __float_as_int(w));
    }
}

// ---- agg layer1 (CSR gather, unroll 4) + beta/bias + BinActive -> sig2x/a2v
__global__ __launch_bounds__(256) void agg1_fused_k(const short2* __restrict__ dots,
                                                    const float* __restrict__ a1,
                                                    const int2* __restrict__ csr1,
                                                    const int* __restrict__ offs,
                                                    const int* __restrict__ deg,
                                                    const float* __restrict__ dinv,
                                                    const float2* __restrict__ beta1_2,
                                                    const float2* __restrict__ b1_2,
                                                    u64* __restrict__ sig2x,
                                                    float* __restrict__ a2v, int n) {
    int tid = threadIdx.x;
    int wave = tid >> 6, l = tid & 63;
    int i = blockIdx.x * 4 + wave;
    if (i >= n) return;
    float di = dinv[i];
    float ts = di * di * a1[i];
    short2 ds = dots[(size_t)i * 64 + l];
    float acc0 = ts * (float)ds.x;
    float acc1 = ts * (float)ds.y;
    int off = offs[i], d = deg[i];
    int k = 0;
    for (; k + 4 <= d; k += 4) {
        int2 e0 = csr1[off+k], e1 = csr1[off+k+1], e2 = csr1[off+k+2], e3 = csr1[off+k+3];
        float t0 = __int_as_float(e0.y);
        float t1 = __int_as_float(e1.y);
        float t2 = __int_as_float(e2.y);
        float t3 = __int_as_float(e3.y);
        short2 d0 = dots[(size_t)e0.x * 64 + l];
        short2 d1 = dots[(size_t)e1.x * 64 + l];
        short2 d2 = dots[(size_t)e2.x * 64 + l];
        short2 d3 = dots[(size_t)e3.x * 64 + l];
        acc0 += t0*(float)d0.x + t1*(float)d1.x + t2*(float)d2.x + t3*(float)d3.x;
        acc1 += t0*(float)d0.y + t1*(float)d1.y + t2*(float)d2.y + t3*(float)d3.y;
    }
    for (; k < d; ++k) {
        int2 ew = csr1[off + k];
        float t = __int_as_float(ew.y);
        short2 dv = dots[(size_t)ew.x * 64 + l];
        acc0 += t * (float)dv.x;
        acc1 += t * (float)dv.y;
    }
    float2 be = beta1_2[l], bb = b1_2[l];
    acc0 = be.x * acc0 + bb.x;                  // hidden features 2l, 2l+1
    acc1 = be.y * acc1 + bb.y;
    float asum = fabsf(acc0) + fabsf(acc1);
    for (int m = 32; m >= 1; m >>= 1) asum += __shfl_xor(asum, m);
    u64 s0 = __ballot(acc0 > 0.f);              // even features
    u64 s1 = __ballot(acc1 > 0.f);              // odd features
    if (l == 0) {
        ulonglong2 pk; pk.x = s0; pk.y = s1;
        *(ulonglong2*)&sig2x[2 * (size_t)i] = pk;
        a2v[i] = asum * (1.0f / 128.0f);
    }
}

// ---- rebake csrw: {r, w} -> {r, w*a2v[r]} (in place) -----------------------
__global__ __launch_bounds__(256) void rebake_k(int2* __restrict__ csrw,
                                                const float* __restrict__ a2v, int e) {
    int i = blockIdx.x * blockDim.x + threadIdx.x;
    if (i < e) {
        int2 ew = csrw[i];
        csrw[i] = make_int2(ew.x, __float_as_int(__int_as_float(ew.y) * a2v[ew.x]));
    }
}

// ---- agg layer2 sign-domain + GEMV (conflict-free) + softmax ---------------
// 64 nodes per block (4 waves x 16) amortizes the 32KB SW LDS fill
__global__ __launch_bounds__(256) void aggz2_fused_k(const u64* __restrict__ sig2x,
                                                     const float* __restrict__ a2v,
                                                     const int2* __restrict__ csrw,
                                                     const int* __restrict__ offs,
                                                     const int* __restrict__ deg,
                                                     const float* __restrict__ dinv,
                                                     const float4* __restrict__ sw4,
                                                     const float* __restrict__ b2,
                                                     float* __restrict__ out, int n) {
    __shared__ float sw[CLS * HID];      // [g][class][m], 32 KB
    __shared__ float zbuf[4][HID];       // per-wave z vector
    int tid = threadIdx.x;
    for (int idx = tid; idx < CLS * HID / 4; idx += 256)
        *(float4*)&sw[idx * 4] = sw4[idx];
    __syncthreads();
    int wave = tid >> 6, l = tid & 63;
    float bias = b2[l];
    for (int q = 0; q < 16; ++q) {
        int i = blockIdx.x * 64 + wave * 16 + q;
        if (i >= n) continue;
        float di = dinv[i];
        float ts = di * di * a2v[i];
        ulonglong2 ws = *(const ulonglong2*)&sig2x[2 * (size_t)i];
        float z0 = ((ws.x >> l) & 1) ? ts : -ts;   // feature 2l
        float z1 = ((ws.y >> l) & 1) ? ts : -ts;   // feature 2l+1
        int off = offs[i], d = deg[i];
        int k = 0;
        for (; k + 4 <= d; k += 4) {
            int2 e0 = csrw[off+k], e1 = csrw[off+k+1], e2 = csrw[off+k+2], e3 = csrw[off+k+3];
            ulonglong2 g0 = *(const ulonglong2*)&sig2x[2 * (size_t)e0.x];
            ulonglong2 g1 = *(const ulonglong2*)&sig2x[2 * (size_t)e1.x];
            ulonglong2 g2 = *(const ulonglong2*)&sig2x[2 * (size_t)e2.x];
            ulonglong2 g3 = *(const ulonglong2*)&sig2x[2 * (size_t)e3.x];
            float t0 = __int_as_float(e0.y);
            float t1 = __int_as_float(e1.y);
            float t2 = __int_as_float(e2.y);
            float t3 = __int_as_float(e3.y);
            z0 += (((g0.x>>l)&1) ? t0 : -t0) + (((g1.x>>l)&1) ? t1 : -t1)
                + (((g2.x>>l)&1) ? t2 : -t2) + (((g3.x>>l)&1) ? t3 : -t3);
            z1 += (((g0.y>>l)&1) ? t0 : -t0) + (((g1.y>>l)&1) ? t1 : -t1)
                + (((g2.y>>l)&1) ? t2 : -t2) + (((g3.y>>l)&1) ? t3 : -t3);
        }
        for (; k < d; ++k) {
            int2 ew = csrw[off + k];
            ulonglong2 gs = *(const ulonglong2*)&sig2x[2 * (size_t)ew.x];
            float t = __int_as_float(ew.y);
            z0 += ((gs.x >> l) & 1) ? t : -t;
            z1 += ((gs.y >> l) & 1) ? t : -t;
        }
        // publish z (features 2l, 2l+1) for the wave; same-wave RAW, no barrier
        ((float2*)&zbuf[wave][0])[l] = make_float2(z0, z1);
        float o = bias;
#pragma unroll
        for (int g = 0; g < 32; ++g) {
            float4 zz = *(const float4*)&zbuf[wave][g * 4];          // broadcast
            float4 ww = *(const float4*)&sw[g * 256 + l * 4];        // conflict-free b128
            o += zz.x*ww.x + zz.y*ww.y + zz.z*ww.z + zz.w*ww.w;
        }
        // log_softmax over 64 classes (one per lane)
        float m = o;
        for (int k2 = 32; k2 >= 1; k2 >>= 1) m = fmaxf(m, __shfl_xor(m, k2));
        float ev = __expf(o - m);
        float s = ev;
        for (int k2 = 32; k2 >= 1; k2 >>= 1) s += __shfl_xor(s, k2);
        out[(size_t)i * CLS + l] = o - m - __logf(s);
    }
}

// ---------------- launch ----------------
extern "C" void kernel_launch(void* const* d_in, const int* in_sizes, int n_in,
                              void* d_out, int out_size, void* d_ws, size_t ws_size,
                              hipStream_t stream) {
    const float* x  = (const float*)d_in[0];
    const int*   ei = (const int*)d_in[1];
    const float* W1 = (const float*)d_in[2];
    const float* b1 = (const float*)d_in[3];
    const float* W2 = (const float*)d_in[4];
    const float* b2 = (const float*)d_in[5];
    float* out = (float*)d_out;

    const int n = in_sizes[0] / F_IN;   // 50000
    const int e = in_sizes[1] / 2;      // 800000
    const int* row = ei;
    const int* col = ei + e;

    // ---- workspace bump allocator (256B aligned) ----
    char* w = (char*)d_ws;
    size_t off = 0;
    auto alloc = [&](size_t bytes) {
        void* p = w + off;
        off += (bytes + 255) & ~(size_t)255;
        return p;
    };
    int*   deg    = (int*)alloc((size_t)n * 4);     // zeroed
    size_t zero_bytes = off;
    float* psum   = (float*)alloc((size_t)NSB * 512 * 4);
    float* psq    = (float*)alloc((size_t)NSB * 512 * 4);
    float* mu     = (float*)alloc(F_IN * 4);
    float* rinv   = (float*)alloc(F_IN * 4);
    float* dinv   = (float*)alloc((size_t)n * 4);
    float* beta1  = (float*)alloc(HID * 4);
    u64*   sig1   = (u64*)alloc(HID * 8 * 8);
    float* sw4    = (float*)alloc(CLS * HID * 4);
    int*   offs   = (int*)alloc((size_t)n * 4);
    int*   cursor = (int*)alloc((size_t)n * 4);
    int*   bsum   = (int*)alloc(256 * 4);
    int*   boff   = (int*)alloc(256 * 4);
    int2*  csr1   = (int2*)alloc((size_t)e * 8);
    int2*  csrw   = (int2*)alloc((size_t)e * 8);
    short2* dots  = (short2*)alloc((size_t)n * 64 * 4);
    float* a1     = (float*)alloc((size_t)n * 4);
    u64*   sig2x  = (u64*)alloc((size_t)n * 2 * 8);
    float* a2v    = (float*)alloc((size_t)n * 4);
    (void)ws_size;

    hipMemsetAsync(d_ws, 0, zero_bytes, stream);

    int rpb = (n + NSB - 1) / NSB;      // 98
    col_stats_k<<<NSB, 256, 0, stream>>>((const float4*)x, psum, psq, n, rpb);
    stats_reduce_k<<<16, 256, 0, stream>>>(psum, psq, mu, rinv, n);
    pack_w1_k<<<HID, 64, 0, stream>>>(W1, sig1, beta1);
    pack_w2_k<<<CLS, 64, 0, stream>>>(W2, sw4);
    deg_k<<<(e + 255) / 256, 256, 0, stream>>>(col, deg, e);

    int nb = (n + 255) / 256;           // 196
    scan_partial_k<<<nb, 256, 0, stream>>>(deg, bsum, n);
    scan_bsum_k<<<1, 256, 0, stream>>>(bsum, boff, nb);
    scan_final_k<<<nb, 256, 0, stream>>>(deg, boff, offs, cursor, dinv, n);

    bin1_gemm1_k<<<(n + 3) / 4, 256, 0, stream>>>((const float4*)x, (const float4*)mu,
                                                  (const float4*)rinv, sig1, a1, dots, n);
    fill_k<<<(e + 255) / 256, 256, 0, stream>>>(row, col, dinv, a1, cursor, csr1, csrw, e);
    agg1_fused_k<<<(n + 3) / 4, 256, 0, stream>>>(dots, a1, csr1, offs, deg, dinv,
                                                  (const float2*)beta1, (const float2*)b1,
                                                  sig2x, a2v, n);
    rebake_k<<<(e + 255) / 256, 256, 0, stream>>>(csrw, a2v, e);
    aggz2_fused_k<<<(n + 63) / 64, 256, 0, stream>>>(sig2x, a2v, csrw, offs, deg, dinv,
                                                     (const float4*)sw4, b2, out, n);
}

// Round 6
// 384.866 us; speedup vs baseline: 1.1305x; 1.1305x over previous
//
#include <hip/hip_runtime.h>

typedef unsigned long long u64;

#define F_IN 512
#define HID 128
#define CLS 64
#define EPS 1e-5f
#define NSB 512   // col_stats partial blocks

// ---------------- column stats: per-block partials, NO atomics --------------
__global__ __launch_bounds__(256) void col_stats_k(const float4* __restrict__ x4,
                                                   float* __restrict__ psum,
                                                   float* __restrict__ psq,
                                                   int n, int rpb) {
    __shared__ float red[256][9];        // pad 9: spread banks
    int c4 = threadIdx.x & 127;          // column quad 0..127
    int half = threadIdx.x >> 7;         // 0/1 row interleave
    int r0 = blockIdx.x * rpb;
    int r1 = min(n, r0 + rpb);
    float s0=0.f,s1=0.f,s2=0.f,s3=0.f,q0=0.f,q1=0.f,q2=0.f,q3=0.f;
#pragma unroll 4
    for (int r = r0 + half; r < r1; r += 2) {
        float4 v = x4[(size_t)r * 128 + c4];
        s0 += v.x; q0 += v.x * v.x;
        s1 += v.y; q1 += v.y * v.y;
        s2 += v.z; q2 += v.z * v.z;
        s3 += v.w; q3 += v.w * v.w;
    }
    red[threadIdx.x][0]=s0; red[threadIdx.x][1]=s1; red[threadIdx.x][2]=s2; red[threadIdx.x][3]=s3;
    red[threadIdx.x][4]=q0; red[threadIdx.x][5]=q1; red[threadIdx.x][6]=q2; red[threadIdx.x][7]=q3;
    __syncthreads();
    if (half == 0) {
        int c = c4 * 4;
        float* os = &psum[(size_t)blockIdx.x * 512 + c];
        float* oq = &psq [(size_t)blockIdx.x * 512 + c];
        os[0] = s0 + red[c4+128][0]; os[1] = s1 + red[c4+128][1];
        os[2] = s2 + red[c4+128][2]; os[3] = s3 + red[c4+128][3];
        oq[0] = q0 + red[c4+128][4]; oq[1] = q1 + red[c4+128][5];
        oq[2] = q2 + red[c4+128][6]; oq[3] = q3 + red[c4+128][7];
    }
}

// ---------------- reduce partials -> mu, rinv (fused finalize) --------------
__global__ __launch_bounds__(256) void stats_reduce_k(const float* __restrict__ psum,
                                                      const float* __restrict__ psq,
                                                      float* __restrict__ mu,
                                                      float* __restrict__ rinv, int n) {
    __shared__ float reds[256], redq[256];
    int cc = threadIdx.x & 31;
    int bs = threadIdx.x >> 5;           // 0..7 b-slice
    int c = blockIdx.x * 32 + cc;        // 16 blocks x 32 cols
    float s = 0.f, q = 0.f;
#pragma unroll 4
    for (int b = bs; b < NSB; b += 8) {
        s += psum[(size_t)b * 512 + c];
        q += psq [(size_t)b * 512 + c];
    }
    reds[threadIdx.x] = s; redq[threadIdx.x] = q;
    __syncthreads();
    if (bs == 0) {
#pragma unroll
        for (int t = 1; t < 8; ++t) { s += reds[cc + 32*t]; q += redq[cc + 32*t]; }
        float m = s / (float)n;
        float v = q / (float)n - m * m;
        mu[c] = m;
        rinv[c] = rsqrtf(v + EPS);
    }
}

// ---- W1 pack. Feature->bit map (matches bin1 float4 loads):
//      word jw<4 : bit l = feature 4l+jw ; word jw>=4 : bit l = feature 256+4l+jw-4
__global__ __launch_bounds__(64) void pack_w1_k(const float* __restrict__ W,
                                                u64* __restrict__ sig,
                                                float* __restrict__ beta) {
    int j = blockIdx.x;    // hidden col 0..127
    int l = threadIdx.x;   // 0..63
    float asum = 0.f;
#pragma unroll
    for (int jw = 0; jw < 8; ++jw) {
        int f = (jw < 4) ? (4*l + jw) : (256 + 4*l + (jw - 4));
        float v = W[(size_t)f * HID + j];
        asum += fabsf(v);
        u64 b = __ballot(v > 0.0f);
        if (l == 0) sig[jw * HID + j] = b;
    }
    for (int m = 32; m >= 1; m >>= 1) asum += __shfl_xor(asum, m);
    if (l == 0) beta[j] = asum * (1.0f / 512.0f);
}

// ---- W2 pack -> per-class 128-bit signature (even/odd feature words) + beta2
//      bit l of .x = sign(W2[2l][j]); bit l of .y = sign(W2[2l+1][j])
//      (matches agg1's ballot packing of sig2x)
__global__ __launch_bounds__(64) void pack_w2_k(const float* __restrict__ W,
                                                ulonglong2* __restrict__ sigw2,
                                                float* __restrict__ beta2) {
    int j = blockIdx.x;    // class 0..63
    int l = threadIdx.x;   // feature pair 2l, 2l+1
    float v0 = W[(size_t)(2 * l) * CLS + j];
    float v1 = W[(size_t)(2 * l + 1) * CLS + j];
    float asum = fabsf(v0) + fabsf(v1);
    u64 s0 = __ballot(v0 > 0.0f);
    u64 s1 = __ballot(v1 > 0.0f);
    for (int m = 32; m >= 1; m >>= 1) asum += __shfl_xor(asum, m);
    if (l == 0) {
        ulonglong2 t; t.x = s0; t.y = s1;
        sigw2[j] = t;
        beta2[j] = asum * (1.0f / 128.0f);
    }
}

// ---------------- degree ----------------
__global__ __launch_bounds__(256) void deg_k(const int* __restrict__ col,
                                             int* __restrict__ deg, int e) {
    int i = blockIdx.x * blockDim.x + threadIdx.x;
    if (i < e) atomicAdd(&deg[col[i]], 1);
}

// ---------------- exclusive scan of deg -> CSR offsets (+dinv fused) --------
__global__ __launch_bounds__(256) void scan_partial_k(const int* __restrict__ deg,
                                                      int* __restrict__ bsum, int n) {
    __shared__ int lds[256];
    int i = blockIdx.x * 256 + threadIdx.x;
    lds[threadIdx.x] = (i < n) ? deg[i] : 0;
    __syncthreads();
    for (int s = 128; s > 0; s >>= 1) {
        if (threadIdx.x < s) lds[threadIdx.x] += lds[threadIdx.x + s];
        __syncthreads();
    }
    if (threadIdx.x == 0) bsum[blockIdx.x] = lds[0];
}

__global__ __launch_bounds__(256) void scan_bsum_k(const int* __restrict__ bsum,
                                                   int* __restrict__ boff, int nb) {
    __shared__ int lds[256];
    int t = threadIdx.x;
    int v = (t < nb) ? bsum[t] : 0;
    lds[t] = v;
    __syncthreads();
    for (int s = 1; s < 256; s <<= 1) {
        int add = (t >= s) ? lds[t - s] : 0;
        __syncthreads();
        lds[t] += add;
        __syncthreads();
    }
    if (t < nb) boff[t] = lds[t] - v;   // exclusive
}

__global__ __launch_bounds__(256) void scan_final_k(const int* __restrict__ deg,
                                                    const int* __restrict__ boff,
                                                    int* __restrict__ offs,
                                                    int* __restrict__ cursor,
                                                    float* __restrict__ dinv, int n) {
    __shared__ int lds[256];
    int t = threadIdx.x;
    int i = blockIdx.x * 256 + t;
    int v = (i < n) ? deg[i] : 0;
    lds[t] = v;
    __syncthreads();
    for (int s = 1; s < 256; s <<= 1) {
        int add = (t >= s) ? lds[t - s] : 0;
        __syncthreads();
        lds[t] += add;
        __syncthreads();
    }
    int excl = lds[t] - v + boff[blockIdx.x];
    if (i < n) {
        offs[i] = excl; cursor[i] = excl;
        dinv[i] = rsqrtf((float)v + 1.0f);   // +1 self-loop
    }
}

// ---------------- CSR fill: bucket edges by dst, store {row, norm} ----------
__global__ __launch_bounds__(256) void fill_k(const int* __restrict__ row,
                                              const int* __restrict__ col,
                                              const float* __restrict__ dinv,
                                              int* __restrict__ cursor,
                                              int2* __restrict__ csr, int e) {
    int i = blockIdx.x * blockDim.x + threadIdx.x;
    if (i < e) {
        int r = row[i], c = col[i];
        int p = atomicAdd(&cursor[c], 1);
        float w = dinv[r] * dinv[c];
        csr[p] = make_int2(r, __float_as_int(w));
    }
}

// ---------------- layer 1: binarize + XNOR-GEMM -> int16 dots + a1 ----------
__global__ __launch_bounds__(256) void bin1_gemm1_k(const float4* __restrict__ x4,
                                                    const float4* __restrict__ mu4,
                                                    const float4* __restrict__ rinv4,
                                                    const u64* __restrict__ sigW,
                                                    float* __restrict__ a1,
                                                    short2* __restrict__ dots, int n) {
    int tid = threadIdx.x;
    int wave = tid >> 6, l = tid & 63;
    int i = blockIdx.x * 4 + wave;
    if (i >= n) return;
    const float4* xr = x4 + (size_t)i * 128;
    float4 va = xr[l], vb = xr[64 + l];          // features 4l..4l+3, 256+4l..+3
    float4 ma = mu4[l], mb = mu4[64 + l];
    float4 ra = rinv4[l], rb = rinv4[64 + l];
    float t0 = va.x - ma.x, t1 = va.y - ma.y, t2 = va.z - ma.z, t3 = va.w - ma.w;
    float t4 = vb.x - mb.x, t5 = vb.y - mb.y, t6 = vb.z - mb.z, t7 = vb.w - mb.w;
    float asum = fabsf(t0)*ra.x + fabsf(t1)*ra.y + fabsf(t2)*ra.z + fabsf(t3)*ra.w
               + fabsf(t4)*rb.x + fabsf(t5)*rb.y + fabsf(t6)*rb.z + fabsf(t7)*rb.w;
    u64 sx[8];
    sx[0] = __ballot(t0 > 0.f); sx[1] = __ballot(t1 > 0.f);
    sx[2] = __ballot(t2 > 0.f); sx[3] = __ballot(t3 > 0.f);
    sx[4] = __ballot(t4 > 0.f); sx[5] = __ballot(t5 > 0.f);
    sx[6] = __ballot(t6 > 0.f); sx[7] = __ballot(t7 > 0.f);
    for (int m = 32; m >= 1; m >>= 1) asum += __shfl_xor(asum, m);
    if (l == 0) a1[i] = asum * (1.0f / 512.0f);
    int c0 = 0, c1 = 0;
#pragma unroll
    for (int w = 0; w < 8; ++w) {
        c0 += __popcll(sx[w] ^ sigW[w * HID + 2*l]);
        c1 += __popcll(sx[w] ^ sigW[w * HID + 2*l + 1]);
    }
    dots[(size_t)i * 64 + l] = make_short2((short)(512 - 2*c0), (short)(512 - 2*c1));
}

// ---- agg layer1 (CSR gather, unroll 4) + beta/bias + BinActive -> sig2x/a2v
__global__ __launch_bounds__(256) void agg1_fused_k(const short2* __restrict__ dots,
                                                    const float* __restrict__ a1,
                                                    const int2* __restrict__ csr,
                                                    const int* __restrict__ offs,
                                                    const int* __restrict__ deg,
                                                    const float* __restrict__ dinv,
                                                    const float2* __restrict__ beta1_2,
                                                    const float2* __restrict__ b1_2,
                                                    u64* __restrict__ sig2x,
                                                    float* __restrict__ a2v, int n) {
    int tid = threadIdx.x;
    int wave = tid >> 6, l = tid & 63;
    int i = blockIdx.x * 4 + wave;
    if (i >= n) return;
    float di = dinv[i];
    float ts = di * di * a1[i];
    short2 ds = dots[(size_t)i * 64 + l];
    float acc0 = ts * (float)ds.x;
    float acc1 = ts * (float)ds.y;
    int off = offs[i], d = deg[i];
    int k = 0;
    for (; k + 4 <= d; k += 4) {
        int2 e0 = csr[off+k], e1 = csr[off+k+1], e2 = csr[off+k+2], e3 = csr[off+k+3];
        float t0 = __int_as_float(e0.y) * a1[e0.x];
        float t1 = __int_as_float(e1.y) * a1[e1.x];
        float t2 = __int_as_float(e2.y) * a1[e2.x];
        float t3 = __int_as_float(e3.y) * a1[e3.x];
        short2 d0 = dots[(size_t)e0.x * 64 + l];
        short2 d1 = dots[(size_t)e1.x * 64 + l];
        short2 d2 = dots[(size_t)e2.x * 64 + l];
        short2 d3 = dots[(size_t)e3.x * 64 + l];
        acc0 += t0*(float)d0.x + t1*(float)d1.x + t2*(float)d2.x + t3*(float)d3.x;
        acc1 += t0*(float)d0.y + t1*(float)d1.y + t2*(float)d2.y + t3*(float)d3.y;
    }
    for (; k < d; ++k) {
        int2 ew = csr[off + k];
        float t = __int_as_float(ew.y) * a1[ew.x];
        short2 dv = dots[(size_t)ew.x * 64 + l];
        acc0 += t * (float)dv.x;
        acc1 += t * (float)dv.y;
    }
    float2 be = beta1_2[l], bb = b1_2[l];
    acc0 = be.x * acc0 + bb.x;                  // hidden features 2l, 2l+1
    acc1 = be.y * acc1 + bb.y;
    float asum = fabsf(acc0) + fabsf(acc1);
    for (int m = 32; m >= 1; m >>= 1) asum += __shfl_xor(asum, m);
    u64 s0 = __ballot(acc0 > 0.f);              // even features
    u64 s1 = __ballot(acc1 > 0.f);              // odd features
    if (l == 0) {
        ulonglong2 pk; pk.x = s0; pk.y = s1;
        *(ulonglong2*)&sig2x[2 * (size_t)i] = pk;
        a2v[i] = asum * (1.0f / 128.0f);
    }
}

// ---- agg layer2, popcount domain: lane = class, 1 node per wave, no LDS ----
// out[i][c] = beta2_c * sum_e t_e*(128-2*popc(sig_src ^ sigw2_c)) + b2_c
__global__ __launch_bounds__(256) void agg2_pop_k(const u64* __restrict__ sig2x,
                                                  const float* __restrict__ a2v,
                                                  const int2* __restrict__ csr,
                                                  const int* __restrict__ offs,
                                                  const int* __restrict__ deg,
                                                  const float* __restrict__ dinv,
                                                  const ulonglong2* __restrict__ sigw2,
                                                  const float* __restrict__ beta2,
                                                  const float* __restrict__ b2,
                                                  float* __restrict__ out, int n) {
    int tid = threadIdx.x;
    int wave = tid >> 6, l = tid & 63;
    int i = blockIdx.x * 4 + wave;
    if (i >= n) return;
    ulonglong2 wsig = sigw2[l];          // this lane's class signature (coalesced)
    float bet = beta2[l], bias = b2[l];
    float di = dinv[i];
    float ts = di * di * a2v[i];
    ulonglong2 ss = *(const ulonglong2*)&sig2x[2 * (size_t)i];
    int dp = __popcll(ss.x ^ wsig.x) + __popcll(ss.y ^ wsig.y);
    float acc = ts * (float)(128 - 2 * dp);
    int off = offs[i], d = deg[i];
    int k = 0;
    for (; k + 4 <= d; k += 4) {
        int2 e0 = csr[off+k], e1 = csr[off+k+1], e2 = csr[off+k+2], e3 = csr[off+k+3];
        ulonglong2 g0 = *(const ulonglong2*)&sig2x[2 * (size_t)e0.x];
        ulonglong2 g1 = *(const ulonglong2*)&sig2x[2 * (size_t)e1.x];
        ulonglong2 g2 = *(const ulonglong2*)&sig2x[2 * (size_t)e2.x];
        ulonglong2 g3 = *(const ulonglong2*)&sig2x[2 * (size_t)e3.x];
        float t0 = __int_as_float(e0.y) * a2v[e0.x];
        float t1 = __int_as_float(e1.y) * a2v[e1.x];
        float t2 = __int_as_float(e2.y) * a2v[e2.x];
        float t3 = __int_as_float(e3.y) * a2v[e3.x];
        int p0 = __popcll(g0.x ^ wsig.x) + __popcll(g0.y ^ wsig.y);
        int p1 = __popcll(g1.x ^ wsig.x) + __popcll(g1.y ^ wsig.y);
        int p2 = __popcll(g2.x ^ wsig.x) + __popcll(g2.y ^ wsig.y);
        int p3 = __popcll(g3.x ^ wsig.x) + __popcll(g3.y ^ wsig.y);
        acc += t0 * (float)(128 - 2*p0) + t1 * (float)(128 - 2*p1)
             + t2 * (float)(128 - 2*p2) + t3 * (float)(128 - 2*p3);
    }
    for (; k < d; ++k) {
        int2 ew = csr[off + k];
        ulonglong2 gs = *(const ulonglong2*)&sig2x[2 * (size_t)ew.x];
        float t = __int_as_float(ew.y) * a2v[ew.x];
        int p = __popcll(gs.x ^ wsig.x) + __popcll(gs.y ^ wsig.y);
        acc += t * (float)(128 - 2*p);
    }
    float o = bet * acc + bias;
    // log_softmax over 64 classes (one per lane)
    float m = o;
    for (int k2 = 32; k2 >= 1; k2 >>= 1) m = fmaxf(m, __shfl_xor(m, k2));
    float ev = __expf(o - m);
    float s = ev;
    for (int k2 = 32; k2 >= 1; k2 >>= 1) s += __shfl_xor(s, k2);
    out[(size_t)i * CLS + l] = o - m - __logf(s);
}

// ---------------- launch ----------------
extern "C" void kernel_launch(void* const* d_in, const int* in_sizes, int n_in,
                              void* d_out, int out_size, void* d_ws, size_t ws_size,
                              hipStream_t stream) {
    const float* x  = (const float*)d_in[0];
    const int*   ei = (const int*)d_in[1];
    const float* W1 = (const float*)d_in[2];
    const float* b1 = (const float*)d_in[3];
    const float* W2 = (const float*)d_in[4];
    const float* b2 = (const float*)d_in[5];
    float* out = (float*)d_out;

    const int n = in_sizes[0] / F_IN;   // 50000
    const int e = in_sizes[1] / 2;      // 800000
    const int* row = ei;
    const int* col = ei + e;

    // ---- workspace bump allocator (256B aligned) ----
    char* w = (char*)d_ws;
    size_t off = 0;
    auto alloc = [&](size_t bytes) {
        void* p = w + off;
        off += (bytes + 255) & ~(size_t)255;
        return p;
    };
    int*   deg    = (int*)alloc((size_t)n * 4);     // zeroed
    size_t zero_bytes = off;
    float* psum   = (float*)alloc((size_t)NSB * 512 * 4);
    float* psq    = (float*)alloc((size_t)NSB * 512 * 4);
    float* mu     = (float*)alloc(F_IN * 4);
    float* rinv   = (float*)alloc(F_IN * 4);
    float* dinv   = (float*)alloc((size_t)n * 4);
    float* beta1  = (float*)alloc(HID * 4);
    u64*   sig1   = (u64*)alloc(HID * 8 * 8);
    ulonglong2* sigw2 = (ulonglong2*)alloc(CLS * 16);
    float* beta2  = (float*)alloc(CLS * 4);
    int*   offs   = (int*)alloc((size_t)n * 4);
    int*   cursor = (int*)alloc((size_t)n * 4);
    int*   bsum   = (int*)alloc(256 * 4);
    int*   boff   = (int*)alloc(256 * 4);
    int2*  csr    = (int2*)alloc((size_t)e * 8);
    short2* dots  = (short2*)alloc((size_t)n * 64 * 4);
    float* a1     = (float*)alloc((size_t)n * 4);
    u64*   sig2x  = (u64*)alloc((size_t)n * 2 * 8);
    float* a2v    = (float*)alloc((size_t)n * 4);
    (void)ws_size;

    hipMemsetAsync(d_ws, 0, zero_bytes, stream);

    int rpb = (n + NSB - 1) / NSB;      // 98
    col_stats_k<<<NSB, 256, 0, stream>>>((const float4*)x, psum, psq, n, rpb);
    stats_reduce_k<<<16, 256, 0, stream>>>(psum, psq, mu, rinv, n);
    pack_w1_k<<<HID, 64, 0, stream>>>(W1, sig1, beta1);
    pack_w2_k<<<CLS, 64, 0, stream>>>(W2, sigw2, beta2);
    deg_k<<<(e + 255) / 256, 256, 0, stream>>>(col, deg, e);

    int nb = (n + 255) / 256;           // 196
    scan_partial_k<<<nb, 256, 0, stream>>>(deg, bsum, n);
    scan_bsum_k<<<1, 256, 0, stream>>>(bsum, boff, nb);
    scan_final_k<<<nb, 256, 0, stream>>>(deg, boff, offs, cursor, dinv, n);

    bin1_gemm1_k<<<(n + 3) / 4, 256, 0, stream>>>((const float4*)x, (const float4*)mu,
                                                  (const float4*)rinv, sig1, a1, dots, n);
    fill_k<<<(e + 255) / 256, 256, 0, stream>>>(row, col, dinv, cursor, csr, e);
    agg1_fused_k<<<(n + 3) / 4, 256, 0, stream>>>(dots, a1, csr, offs, deg, dinv,
                                                  (const float2*)beta1, (const float2*)b1,
                                                  sig2x, a2v, n);
    agg2_pop_k<<<(n + 3) / 4, 256, 0, stream>>>(sig2x, a2v, csr, offs, deg, dinv,
                                                sigw2, beta2, b2, out, n);
}

// Round 7
// 360.768 us; speedup vs baseline: 1.2060x; 1.0668x over previous
//
#include <hip/hip_runtime.h>

typedef unsigned long long u64;

#define F_IN 512
#define HID 128
#define CLS 64
#define EPS 1e-5f
#define NSB 512   // col_stats partial blocks

// ============ K1: col_stats ∥ deg ∥ pack_w1 ∥ pack_w2 (all independent) =====
__global__ __launch_bounds__(256) void prep_k(const float4* __restrict__ x4,
                                              float* __restrict__ psum,
                                              float* __restrict__ psq,
                                              int n, int rpb,
                                              const int* __restrict__ col,
                                              int* __restrict__ deg, int e, int nbdeg,
                                              const float* __restrict__ W1,
                                              u64* __restrict__ sig1,
                                              float* __restrict__ beta1,
                                              const float* __restrict__ W2,
                                              ulonglong2* __restrict__ sigw2,
                                              float* __restrict__ beta2) {
    __shared__ float red[256][9];
    int b = blockIdx.x;
    int tid = threadIdx.x;
    if (b < NSB) {
        // ---- column stats partials (no atomics) ----
        int c4 = tid & 127;
        int half = tid >> 7;
        int r0 = b * rpb;
        int r1 = min(n, r0 + rpb);
        float s0=0.f,s1=0.f,s2=0.f,s3=0.f,q0=0.f,q1=0.f,q2=0.f,q3=0.f;
#pragma unroll 4
        for (int r = r0 + half; r < r1; r += 2) {
            float4 v = x4[(size_t)r * 128 + c4];
            s0 += v.x; q0 += v.x * v.x;
            s1 += v.y; q1 += v.y * v.y;
            s2 += v.z; q2 += v.z * v.z;
            s3 += v.w; q3 += v.w * v.w;
        }
        red[tid][0]=s0; red[tid][1]=s1; red[tid][2]=s2; red[tid][3]=s3;
        red[tid][4]=q0; red[tid][5]=q1; red[tid][6]=q2; red[tid][7]=q3;
        __syncthreads();
        if (half == 0) {
            int c = c4 * 4;
            float* os = &psum[(size_t)b * 512 + c];
            float* oq = &psq [(size_t)b * 512 + c];
            os[0] = s0 + red[c4+128][0]; os[1] = s1 + red[c4+128][1];
            os[2] = s2 + red[c4+128][2]; os[3] = s3 + red[c4+128][3];
            oq[0] = q0 + red[c4+128][4]; oq[1] = q1 + red[c4+128][5];
            oq[2] = q2 + red[c4+128][6]; oq[3] = q3 + red[c4+128][7];
        }
    } else if (b < NSB + nbdeg) {
        // ---- degree histogram ----
        int i = (b - NSB) * 256 + tid;
        if (i < e) atomicAdd(&deg[col[i]], 1);
    } else if (b < NSB + nbdeg + 32) {
        // ---- pack W1: wave per hidden col j ----
        int wave = tid >> 6, l = tid & 63;
        int j = (b - NSB - nbdeg) * 4 + wave;   // 0..127
        float asum = 0.f;
#pragma unroll
        for (int jw = 0; jw < 8; ++jw) {
            int f = (jw < 4) ? (4*l + jw) : (256 + 4*l + (jw - 4));
            float v = W1[(size_t)f * HID + j];
            asum += fabsf(v);
            u64 bb = __ballot(v > 0.0f);
            if (l == 0) sig1[jw * HID + j] = bb;
        }
        for (int m = 32; m >= 1; m >>= 1) asum += __shfl_xor(asum, m);
        if (l == 0) beta1[j] = asum * (1.0f / 512.0f);
    } else {
        // ---- pack W2: wave per class j; 128-bit signature (even/odd words) --
        int wave = tid >> 6, l = tid & 63;
        int j = (b - NSB - nbdeg - 32) * 4 + wave;   // 0..63
        float v0 = W2[(size_t)(2 * l) * CLS + j];
        float v1 = W2[(size_t)(2 * l + 1) * CLS + j];
        float asum = fabsf(v0) + fabsf(v1);
        u64 s0 = __ballot(v0 > 0.0f);
        u64 s1 = __ballot(v1 > 0.0f);
        for (int m = 32; m >= 1; m >>= 1) asum += __shfl_xor(asum, m);
        if (l == 0) {
            ulonglong2 t; t.x = s0; t.y = s1;
            sigw2[j] = t;
            beta2[j] = asum * (1.0f / 128.0f);
        }
    }
}

// ============ K2: stats_reduce ∥ scan_partial ===============================
__global__ __launch_bounds__(256) void mid_k(const float* __restrict__ psum,
                                             const float* __restrict__ psq,
                                             float* __restrict__ mu,
                                             float* __restrict__ rinv, int n,
                                             const int* __restrict__ deg,
                                             int* __restrict__ bsum) {
    __shared__ float reds[256], redq[256];
    __shared__ int lds[256];
    int b = blockIdx.x;
    int t = threadIdx.x;
    if (b < 16) {
        // ---- reduce col-stat partials -> mu, rinv ----
        int cc = t & 31;
        int bs = t >> 5;
        int c = b * 32 + cc;
        float s = 0.f, q = 0.f;
#pragma unroll 4
        for (int p = bs; p < NSB; p += 8) {
            s += psum[(size_t)p * 512 + c];
            q += psq [(size_t)p * 512 + c];
        }
        reds[t] = s; redq[t] = q;
        __syncthreads();
        if (bs == 0) {
#pragma unroll
            for (int u = 1; u < 8; ++u) { s += reds[cc + 32*u]; q += redq[cc + 32*u]; }
            float m = s / (float)n;
            float v = q / (float)n - m * m;
            mu[c] = m;
            rinv[c] = rsqrtf(v + EPS);
        }
    } else {
        // ---- per-block degree sums for scan ----
        int blk = b - 16;
        int i = blk * 256 + t;
        lds[t] = (i < n) ? deg[i] : 0;
        __syncthreads();
        for (int s = 128; s > 0; s >>= 1) {
            if (t < s) lds[t] += lds[t + s];
            __syncthreads();
        }
        if (t == 0) bsum[blk] = lds[0];
    }
}

__global__ __launch_bounds__(256) void scan_bsum_k(const int* __restrict__ bsum,
                                                   int* __restrict__ boff, int nb) {
    __shared__ int lds[256];
    int t = threadIdx.x;
    int v = (t < nb) ? bsum[t] : 0;
    lds[t] = v;
    __syncthreads();
    for (int s = 1; s < 256; s <<= 1) {
        int add = (t >= s) ? lds[t - s] : 0;
        __syncthreads();
        lds[t] += add;
        __syncthreads();
    }
    if (t < nb) boff[t] = lds[t] - v;   // exclusive
}

__global__ __launch_bounds__(256) void scan_final_k(const int* __restrict__ deg,
                                                    const int* __restrict__ boff,
                                                    int* __restrict__ offs,
                                                    int* __restrict__ cursor,
                                                    float* __restrict__ dinv, int n) {
    __shared__ int lds[256];
    int t = threadIdx.x;
    int i = blockIdx.x * 256 + t;
    int v = (i < n) ? deg[i] : 0;
    lds[t] = v;
    __syncthreads();
    for (int s = 1; s < 256; s <<= 1) {
        int add = (t >= s) ? lds[t - s] : 0;
        __syncthreads();
        lds[t] += add;
        __syncthreads();
    }
    int excl = lds[t] - v + boff[blockIdx.x];
    if (i < n) {
        offs[i] = excl; cursor[i] = excl;
        dinv[i] = rsqrtf((float)v + 1.0f);   // +1 self-loop
    }
}

// ============ K5: bin1_gemm1 ∥ fill =========================================
__global__ __launch_bounds__(256) void main1_k(const float4* __restrict__ x4,
                                               const float4* __restrict__ mu4,
                                               const float4* __restrict__ rinv4,
                                               const u64* __restrict__ sigW,
                                               float* __restrict__ a1,
                                               short2* __restrict__ dots, int n, int nbin,
                                               const int* __restrict__ row,
                                               const int* __restrict__ col,
                                               const float* __restrict__ dinv,
                                               int* __restrict__ cursor,
                                               int2* __restrict__ csr, int e) {
    int b = blockIdx.x;
    int tid = threadIdx.x;
    if (b < nbin) {
        // ---- layer 1: binarize + XNOR popcount GEMM ----
        int wave = tid >> 6, l = tid & 63;
        int i = b * 4 + wave;
        if (i >= n) return;
        const float4* xr = x4 + (size_t)i * 128;
        float4 va = xr[l], vb = xr[64 + l];
        float4 ma = mu4[l], mb = mu4[64 + l];
        float4 ra = rinv4[l], rb = rinv4[64 + l];
        float t0 = va.x - ma.x, t1 = va.y - ma.y, t2 = va.z - ma.z, t3 = va.w - ma.w;
        float t4 = vb.x - mb.x, t5 = vb.y - mb.y, t6 = vb.z - mb.z, t7 = vb.w - mb.w;
        float asum = fabsf(t0)*ra.x + fabsf(t1)*ra.y + fabsf(t2)*ra.z + fabsf(t3)*ra.w
                   + fabsf(t4)*rb.x + fabsf(t5)*rb.y + fabsf(t6)*rb.z + fabsf(t7)*rb.w;
        u64 sx[8];
        sx[0] = __ballot(t0 > 0.f); sx[1] = __ballot(t1 > 0.f);
        sx[2] = __ballot(t2 > 0.f); sx[3] = __ballot(t3 > 0.f);
        sx[4] = __ballot(t4 > 0.f); sx[5] = __ballot(t5 > 0.f);
        sx[6] = __ballot(t6 > 0.f); sx[7] = __ballot(t7 > 0.f);
        for (int m = 32; m >= 1; m >>= 1) asum += __shfl_xor(asum, m);
        if (l == 0) a1[i] = asum * (1.0f / 512.0f);
        int c0 = 0, c1 = 0;
#pragma unroll
        for (int w = 0; w < 8; ++w) {
            c0 += __popcll(sx[w] ^ sigW[w * HID + 2*l]);
            c1 += __popcll(sx[w] ^ sigW[w * HID + 2*l + 1]);
        }
        dots[(size_t)i * 64 + l] = make_short2((short)(512 - 2*c0), (short)(512 - 2*c1));
    } else {
        // ---- CSR fill ----
        int i = (b - nbin) * 256 + tid;
        if (i < e) {
            int r = row[i], c = col[i];
            int p = atomicAdd(&cursor[c], 1);
            float w = dinv[r] * dinv[c];
            csr[p] = make_int2(r, __float_as_int(w));
        }
    }
}

// ============ K6: agg layer1 (CSR gather, unroll 8) + BinActive -> sig2x/a2v
__global__ __launch_bounds__(256) void agg1_fused_k(const short2* __restrict__ dots,
                                                    const float* __restrict__ a1,
                                                    const int2* __restrict__ csr,
                                                    const int* __restrict__ offs,
                                                    const int* __restrict__ deg,
                                                    const float* __restrict__ dinv,
                                                    const float2* __restrict__ beta1_2,
                                                    const float2* __restrict__ b1_2,
                                                    u64* __restrict__ sig2x,
                                                    float* __restrict__ a2v, int n) {
    int tid = threadIdx.x;
    int wave = tid >> 6, l = tid & 63;
    int i = blockIdx.x * 4 + wave;
    if (i >= n) return;
    float di = dinv[i];
    float ts = di * di * a1[i];
    short2 ds = dots[(size_t)i * 64 + l];
    float acc0 = ts * (float)ds.x;
    float acc1 = ts * (float)ds.y;
    int off = offs[i], d = deg[i];
    int k = 0;
    for (; k + 8 <= d; k += 8) {
        int2 ee[8]; float tt[8]; short2 dd[8];
#pragma unroll
        for (int u = 0; u < 8; ++u) ee[u] = csr[off + k + u];
#pragma unroll
        for (int u = 0; u < 8; ++u) tt[u] = __int_as_float(ee[u].y) * a1[ee[u].x];
#pragma unroll
        for (int u = 0; u < 8; ++u) dd[u] = dots[(size_t)ee[u].x * 64 + l];
#pragma unroll
        for (int u = 0; u < 8; ++u) {
            acc0 += tt[u] * (float)dd[u].x;
            acc1 += tt[u] * (float)dd[u].y;
        }
    }
    for (; k < d; ++k) {
        int2 ew = csr[off + k];
        float t = __int_as_float(ew.y) * a1[ew.x];
        short2 dv = dots[(size_t)ew.x * 64 + l];
        acc0 += t * (float)dv.x;
        acc1 += t * (float)dv.y;
    }
    float2 be = beta1_2[l], bb = b1_2[l];
    acc0 = be.x * acc0 + bb.x;                  // hidden features 2l, 2l+1
    acc1 = be.y * acc1 + bb.y;
    float asum = fabsf(acc0) + fabsf(acc1);
    for (int m = 32; m >= 1; m >>= 1) asum += __shfl_xor(asum, m);
    u64 s0 = __ballot(acc0 > 0.f);              // even features
    u64 s1 = __ballot(acc1 > 0.f);              // odd features
    if (l == 0) {
        ulonglong2 pk; pk.x = s0; pk.y = s1;
        *(ulonglong2*)&sig2x[2 * (size_t)i] = pk;
        a2v[i] = asum * (1.0f / 128.0f);
    }
}

// ============ K7: agg layer2 popcount domain (unroll 8) + log_softmax =======
__global__ __launch_bounds__(256) void agg2_pop_k(const u64* __restrict__ sig2x,
                                                  const float* __restrict__ a2v,
                                                  const int2* __restrict__ csr,
                                                  const int* __restrict__ offs,
                                                  const int* __restrict__ deg,
                                                  const float* __restrict__ dinv,
                                                  const ulonglong2* __restrict__ sigw2,
                                                  const float* __restrict__ beta2,
                                                  const float* __restrict__ b2,
                                                  float* __restrict__ out, int n) {
    int tid = threadIdx.x;
    int wave = tid >> 6, l = tid & 63;
    int i = blockIdx.x * 4 + wave;
    if (i >= n) return;
    ulonglong2 wsig = sigw2[l];          // this lane's class signature
    float bet = beta2[l], bias = b2[l];
    float di = dinv[i];
    float ts = di * di * a2v[i];
    ulonglong2 ss = *(const ulonglong2*)&sig2x[2 * (size_t)i];
    int dp = __popcll(ss.x ^ wsig.x) + __popcll(ss.y ^ wsig.y);
    float acc = ts * (float)(128 - 2 * dp);
    int off = offs[i], d = deg[i];
    int k = 0;
    for (; k + 8 <= d; k += 8) {
        int2 ee[8]; float tt[8]; ulonglong2 gg[8];
#pragma unroll
        for (int u = 0; u < 8; ++u) ee[u] = csr[off + k + u];
#pragma unroll
        for (int u = 0; u < 8; ++u) tt[u] = __int_as_float(ee[u].y) * a2v[ee[u].x];
#pragma unroll
        for (int u = 0; u < 8; ++u) gg[u] = *(const ulonglong2*)&sig2x[2 * (size_t)ee[u].x];
#pragma unroll
        for (int u = 0; u < 8; ++u) {
            int p = __popcll(gg[u].x ^ wsig.x) + __popcll(gg[u].y ^ wsig.y);
            acc += tt[u] * (float)(128 - 2 * p);
        }
    }
    for (; k < d; ++k) {
        int2 ew = csr[off + k];
        ulonglong2 gs = *(const ulonglong2*)&sig2x[2 * (size_t)ew.x];
        float t = __int_as_float(ew.y) * a2v[ew.x];
        int p = __popcll(gs.x ^ wsig.x) + __popcll(gs.y ^ wsig.y);
        acc += t * (float)(128 - 2 * p);
    }
    float o = bet * acc + bias;
    // log_softmax over 64 classes (one per lane)
    float m = o;
    for (int k2 = 32; k2 >= 1; k2 >>= 1) m = fmaxf(m, __shfl_xor(m, k2));
    float ev = __expf(o - m);
    float s = ev;
    for (int k2 = 32; k2 >= 1; k2 >>= 1) s += __shfl_xor(s, k2);
    out[(size_t)i * CLS + l] = o - m - __logf(s);
}

// ---------------- launch ----------------
extern "C" void kernel_launch(void* const* d_in, const int* in_sizes, int n_in,
                              void* d_out, int out_size, void* d_ws, size_t ws_size,
                              hipStream_t stream) {
    const float* x  = (const float*)d_in[0];
    const int*   ei = (const int*)d_in[1];
    const float* W1 = (const float*)d_in[2];
    const float* b1 = (const float*)d_in[3];
    const float* W2 = (const float*)d_in[4];
    const float* b2 = (const float*)d_in[5];
    float* out = (float*)d_out;

    const int n = in_sizes[0] / F_IN;   // 50000
    const int e = in_sizes[1] / 2;      // 800000
    const int* row = ei;
    const int* col = ei + e;

    // ---- workspace bump allocator (256B aligned) ----
    char* w = (char*)d_ws;
    size_t off = 0;
    auto alloc = [&](size_t bytes) {
        void* p = w + off;
        off += (bytes + 255) & ~(size_t)255;
        return p;
    };
    int*   deg    = (int*)alloc((size_t)n * 4);     // zeroed
    size_t zero_bytes = off;
    float* psum   = (float*)alloc((size_t)NSB * 512 * 4);
    float* psq    = (float*)alloc((size_t)NSB * 512 * 4);
    float* mu     = (float*)alloc(F_IN * 4);
    float* rinv   = (float*)alloc(F_IN * 4);
    float* dinv   = (float*)alloc((size_t)n * 4);
    float* beta1  = (float*)alloc(HID * 4);
    u64*   sig1   = (u64*)alloc(HID * 8 * 8);
    ulonglong2* sigw2 = (ulonglong2*)alloc(CLS * 16);
    float* beta2  = (float*)alloc(CLS * 4);
    int*   offs   = (int*)alloc((size_t)n * 4);
    int*   cursor = (int*)alloc((size_t)n * 4);
    int*   bsum   = (int*)alloc(256 * 4);
    int*   boff   = (int*)alloc(256 * 4);
    int2*  csr    = (int2*)alloc((size_t)e * 8);
    short2* dots  = (short2*)alloc((size_t)n * 64 * 4);
    float* a1     = (float*)alloc((size_t)n * 4);
    u64*   sig2x  = (u64*)alloc((size_t)n * 2 * 8);
    float* a2v    = (float*)alloc((size_t)n * 4);
    (void)ws_size;

    hipMemsetAsync(deg, 0, zero_bytes, stream);

    int rpb = (n + NSB - 1) / NSB;          // 98
    int nbdeg = (e + 255) / 256;            // 3125
    int nb = (n + 255) / 256;               // 196
    int nbin = (n + 3) / 4;                 // 12500

    // K1: col_stats ∥ deg ∥ pack_w1 ∥ pack_w2
    prep_k<<<NSB + nbdeg + 32 + 16, 256, 0, stream>>>(
        (const float4*)x, psum, psq, n, rpb,
        col, deg, e, nbdeg,
        W1, sig1, beta1, W2, sigw2, beta2);

    // K2: stats_reduce ∥ scan_partial
    mid_k<<<16 + nb, 256, 0, stream>>>(psum, psq, mu, rinv, n, deg, bsum);
    scan_bsum_k<<<1, 256, 0, stream>>>(bsum, boff, nb);
    scan_final_k<<<nb, 256, 0, stream>>>(deg, boff, offs, cursor, dinv, n);

    // K5: bin1 ∥ fill
    main1_k<<<nbin + nbdeg, 256, 0, stream>>>(
        (const float4*)x, (const float4*)mu, (const float4*)rinv, sig1, a1, dots, n, nbin,
        row, col, dinv, cursor, csr, e);

    agg1_fused_k<<<nbin, 256, 0, stream>>>(dots, a1, csr, offs, deg, dinv,
                                           (const float2*)beta1, (const float2*)b1,
                                           sig2x, a2v, n);
    agg2_pop_k<<<nbin, 256, 0, stream>>>(sig2x, a2v, csr, offs, deg, dinv,
                                         sigw2, beta2, b2, out, n);
}